// Round 1
// baseline (1008.220 us; speedup 1.0000x reference)
//
#include <hip/hip_runtime.h>
#include <hip/hip_bf16.h>

#define DD 512
#define BM 32
#define THREADS 512

typedef __attribute__((ext_vector_type(8))) short short8;   // 8 bf16 = 4 VGPRs (MFMA A/B frag)
typedef __attribute__((ext_vector_type(4))) float f32x4;    // MFMA C/D frag

__device__ __forceinline__ unsigned short f2bf(float f) {
  union { float f; unsigned u; } v; v.f = f;
  unsigned r = v.u + 0x7FFFu + ((v.u >> 16) & 1u);  // RNE
  return (unsigned short)(r >> 16);
}
__device__ __forceinline__ float bf2f(unsigned short u) {
  union { unsigned u; float f; } v; v.u = ((unsigned)u) << 16;
  return v.f;
}

// kernel (K x N) fp32 -> Bt (N x K) bf16, coalesced both sides via LDS tile
__global__ void prep_bt(const float* __restrict__ W, unsigned short* __restrict__ Bt) {
  __shared__ float tile[32][33];
  const int k0 = blockIdx.x * 32, n0 = blockIdx.y * 32;
  const int tx = threadIdx.x, ty = threadIdx.y;   // 32 x 8
  #pragma unroll
  for (int i = 0; i < 32; i += 8)
    tile[ty + i][tx] = W[(size_t)(k0 + ty + i) * DD + (n0 + tx)];
  __syncthreads();
  #pragma unroll
  for (int i = 0; i < 32; i += 8)
    Bt[(size_t)(n0 + ty + i) * DD + (k0 + tx)] = f2bf(tile[tx][ty + i]);
}

// Fused: LN -> relu -> (bf16 cast) -> GEMM vs Bt -> +x +bias
// block: 32 rows x full 512 cols; 8 waves as 2(M) x 4(N), wave tile 16x128.
__global__ __launch_bounds__(THREADS, 4)
void fused_ln_gemm(const float* __restrict__ x, const float* __restrict__ lns,
                   const float* __restrict__ lnb, const unsigned short* __restrict__ Bt,
                   const float* __restrict__ bias, float* __restrict__ out) {
  __shared__ unsigned short Alds[BM * 512];   // h bf16, XOR-swizzled rows (1KB row)
  __shared__ unsigned short Xlds[BM * 528];   // x bf16, padded stride (1056B row)

  const int t = threadIdx.x;
  const long row0 = (long)blockIdx.x * BM;

  // ---------------- LN + relu phase: 16 threads per row ----------------
  {
    const int r = t >> 4, g = t & 15;
    const float* xr = x + (row0 + r) * DD + g * 4;
    float4 v[8];
    float s = 0.f, s2 = 0.f;
    #pragma unroll
    for (int i = 0; i < 8; ++i) {
      v[i] = *(const float4*)(xr + i * 64);
      s  += (v[i].x + v[i].y) + (v[i].z + v[i].w);
      s2 += v[i].x * v[i].x + v[i].y * v[i].y + v[i].z * v[i].z + v[i].w * v[i].w;
    }
    #pragma unroll
    for (int m = 1; m < 16; m <<= 1) {   // 16-lane group reduce (within wave)
      s  += __shfl_xor(s,  m, 64);
      s2 += __shfl_xor(s2, m, 64);
    }
    const float mu   = s * (1.f / 512.f);
    const float var  = fmaxf(s2 * (1.f / 512.f) - mu * mu, 0.f);
    const float rstd = rsqrtf(var + 1e-6f);
    #pragma unroll
    for (int i = 0; i < 8; ++i) {
      const int c = g * 4 + i * 64;
      const float4 sc = *(const float4*)(lns + c);
      const float4 bi = *(const float4*)(lnb + c);
      float h0 = fmaxf((v[i].x - mu) * rstd * sc.x + bi.x, 0.f);
      float h1 = fmaxf((v[i].y - mu) * rstd * sc.y + bi.y, 0.f);
      float h2 = fmaxf((v[i].z - mu) * rstd * sc.z + bi.z, 0.f);
      float h3 = fmaxf((v[i].w - mu) * rstd * sc.w + bi.w, 0.f);
      ushort4 hu = { f2bf(h0), f2bf(h1), f2bf(h2), f2bf(h3) };
      ushort4 xu = { f2bf(v[i].x), f2bf(v[i].y), f2bf(v[i].z), f2bf(v[i].w) };
      // A: byte addr (r*1024 + c*2) ^ ((r&7)<<4)  — 8B-aligned stays 8B-aligned
      unsigned a = (unsigned)(r * 1024 + g * 8 + i * 128) ^ (unsigned)((r & 7) << 4);
      *(ushort4*)((char*)Alds + a) = hu;
      *(ushort4*)(&Xlds[r * 528 + c]) = xu;
    }
  }
  __syncthreads();

  // ---------------- GEMM phase (no barriers in K-loop) ----------------
  const int lane = t & 63, lo = lane & 15, hi = lane >> 4;
  const int w = t >> 6, wm = w >> 2, wn = w & 3;

  const int rowA = wm * 16 + lo;
  const unsigned abase = (unsigned)(rowA * 1024 + hi * 16);
  const unsigned aswz  = (unsigned)((rowA & 7) << 4);
  // B frag base: column n = wn*128 + nt*16 + lo; lane holds k = kt*32 + hi*8 .. +7
  const short8* bptr = (const short8*)(Bt + (size_t)(wn * 128 + lo) * DD + hi * 8);

  f32x4 acc[8] = {};
  #pragma unroll 2
  for (int kt = 0; kt < 16; ++kt) {
    const short8 a = *(const short8*)((const char*)Alds + ((abase + kt * 64) ^ aswz));
    #pragma unroll
    for (int nt = 0; nt < 8; ++nt) {
      const short8 b = bptr[nt * 1024 + kt * 4];   // 16B units: nt*16KB + kt*64B
      acc[nt] = __builtin_amdgcn_mfma_f32_16x16x32_bf16(a, b, acc[nt], 0, 0, 0);
    }
  }

  // ---------------- epilogue: out = x + acc + bias ----------------
  #pragma unroll
  for (int nt = 0; nt < 8; ++nt) {
    const int col = wn * 128 + nt * 16 + lo;
    const float bv = bias[col];
    #pragma unroll
    for (int q = 0; q < 4; ++q) {
      const int rloc = wm * 16 + hi * 4 + q;       // C/D: row = 4*hi + reg
      const float xv = bf2f(Xlds[rloc * 528 + col]);
      out[(row0 + rloc) * DD + col] = xv + acc[nt][q] + bv;
    }
  }
}

extern "C" void kernel_launch(void* const* d_in, const int* in_sizes, int n_in,
                              void* d_out, int out_size, void* d_ws, size_t ws_size,
                              hipStream_t stream) {
  const float* x    = (const float*)d_in[0];
  const float* lns  = (const float*)d_in[1];
  const float* lnb  = (const float*)d_in[2];
  const float* W    = (const float*)d_in[3];
  const float* bias = (const float*)d_in[4];
  float* out = (float*)d_out;
  unsigned short* Bt = (unsigned short*)d_ws;   // 512*512*2 = 512KB scratch

  const int nrows = in_sizes[0] / DD;

  dim3 tb(32, 8), tg(DD / 32, DD / 32);
  prep_bt<<<tg, tb, 0, stream>>>(W, Bt);
  fused_ln_gemm<<<nrows / BM, THREADS, 0, stream>>>(x, lns, lnb, Bt, bias, out);
}

// Round 2
// 583.174 us; speedup vs baseline: 1.7288x; 1.7288x over previous
//
#include <hip/hip_runtime.h>
#include <hip/hip_bf16.h>

#define DD 512
#define BM 32
#define THREADS 512

typedef __attribute__((ext_vector_type(8))) short short8;   // 8 bf16 = 4 VGPRs (MFMA A/B frag)
typedef __attribute__((ext_vector_type(4))) float f32x4;    // MFMA C/D frag

__device__ __forceinline__ unsigned short f2bf(float f) {
  union { float f; unsigned u; } v; v.f = f;
  unsigned r = v.u + 0x7FFFu + ((v.u >> 16) & 1u);  // RNE
  return (unsigned short)(r >> 16);
}
__device__ __forceinline__ float bf2f(unsigned short u) {
  union { unsigned u; float f; } v; v.u = ((unsigned)u) << 16;
  return v.f;
}

// kernel (K x N) fp32 -> Bt (N x K) bf16, coalesced both sides via LDS tile
__global__ void prep_bt(const float* __restrict__ W, unsigned short* __restrict__ Bt) {
  __shared__ float tile[32][33];
  const int k0 = blockIdx.x * 32, n0 = blockIdx.y * 32;
  const int tx = threadIdx.x, ty = threadIdx.y;   // 32 x 8
  #pragma unroll
  for (int i = 0; i < 32; i += 8)
    tile[ty + i][tx] = W[(size_t)(k0 + ty + i) * DD + (n0 + tx)];
  __syncthreads();
  #pragma unroll
  for (int i = 0; i < 32; i += 8)
    Bt[(size_t)(n0 + ty + i) * DD + (k0 + tx)] = f2bf(tile[tx][ty + i]);
}

// Fused: LN -> relu -> (bf16 cast) -> GEMM vs Bt -> +x +bias
// block: 32 rows x full 512 cols; 8 waves each own a 32x64 output strip.
__global__ __launch_bounds__(THREADS, 4)
void fused_ln_gemm(const float* __restrict__ x, const float* __restrict__ lns,
                   const float* __restrict__ lnb, const unsigned short* __restrict__ Bt,
                   const float* __restrict__ bias, float* __restrict__ out) {
  __shared__ unsigned short Alds[BM * 512];   // h bf16, XOR-swizzled rows (1KB row)
  __shared__ unsigned short Xlds[BM * 528];   // x bf16, padded stride (1056B row)

  const int t = threadIdx.x;
  const long row0 = (long)blockIdx.x * BM;

  // ---------------- LN + relu phase: 16 threads per row ----------------
  {
    const int r = t >> 4, g = t & 15;
    const float* xr = x + (row0 + r) * DD + g * 4;
    float4 v[8];
    float s = 0.f, s2 = 0.f;
    #pragma unroll
    for (int i = 0; i < 8; ++i) {
      v[i] = *(const float4*)(xr + i * 64);
      s  += (v[i].x + v[i].y) + (v[i].z + v[i].w);
      s2 += v[i].x * v[i].x + v[i].y * v[i].y + v[i].z * v[i].z + v[i].w * v[i].w;
    }
    #pragma unroll
    for (int m = 1; m < 16; m <<= 1) {   // 16-lane group reduce (within wave)
      s  += __shfl_xor(s,  m, 64);
      s2 += __shfl_xor(s2, m, 64);
    }
    const float mu   = s * (1.f / 512.f);
    const float var  = fmaxf(s2 * (1.f / 512.f) - mu * mu, 0.f);
    const float rstd = rsqrtf(var + 1e-6f);
    #pragma unroll
    for (int i = 0; i < 8; ++i) {
      const int c = g * 4 + i * 64;
      const float4 sc = *(const float4*)(lns + c);
      const float4 bi = *(const float4*)(lnb + c);
      float h0 = fmaxf((v[i].x - mu) * rstd * sc.x + bi.x, 0.f);
      float h1 = fmaxf((v[i].y - mu) * rstd * sc.y + bi.y, 0.f);
      float h2 = fmaxf((v[i].z - mu) * rstd * sc.z + bi.z, 0.f);
      float h3 = fmaxf((v[i].w - mu) * rstd * sc.w + bi.w, 0.f);
      ushort4 hu = { f2bf(h0), f2bf(h1), f2bf(h2), f2bf(h3) };
      ushort4 xu = { f2bf(v[i].x), f2bf(v[i].y), f2bf(v[i].z), f2bf(v[i].w) };
      // A: byte addr (r*1024 + c*2) ^ ((r&7)<<4)  — 8B-aligned stays 8B-aligned
      unsigned a = (unsigned)(r * 1024 + g * 8 + i * 128) ^ (unsigned)((r & 7) << 4);
      *(ushort4*)((char*)Alds + a) = hu;
      *(ushort4*)(&Xlds[r * 528 + c]) = xu;
    }
  }
  __syncthreads();

  // ---------------- GEMM phase (no barriers, depth-2 B prefetch) -------
  const int lane = t & 63, lo = lane & 15, hi = lane >> 4;
  const int wn = t >> 6;                       // 0..7: wave's 64-col strip

  // A frag byte addrs for the two 16-row sub-tiles (m = 0,1)
  unsigned abase0, aswz0, abase1, aswz1;
  {
    const int r0 = lo;        abase0 = (unsigned)(r0 * 1024 + hi * 16); aswz0 = (unsigned)((r0 & 7) << 4);
    const int r1 = 16 + lo;   abase1 = (unsigned)(r1 * 1024 + hi * 16); aswz1 = (unsigned)((r1 & 7) << 4);
  }
  // B: column n = wn*64 + nt*16 + lo; lane holds k = kt*32 + hi*8 .. +7
  const unsigned short* bbase = Bt + (size_t)(wn * 64 + lo) * DD + hi * 8;

#define LOADB(dst, kt)                                                        \
  { dst##0 = *(const short8*)(bbase + 0 * 8192 + (kt) * 32);                  \
    dst##1 = *(const short8*)(bbase + 1 * 8192 + (kt) * 32);                  \
    dst##2 = *(const short8*)(bbase + 2 * 8192 + (kt) * 32);                  \
    dst##3 = *(const short8*)(bbase + 3 * 8192 + (kt) * 32); }

  short8 bA0, bA1, bA2, bA3, bB0, bB1, bB2, bB3, bC0, bC1, bC2, bC3;
  LOADB(bA, 0);
  LOADB(bB, 1);

  f32x4 acc00 = {}, acc01 = {}, acc02 = {}, acc03 = {};
  f32x4 acc10 = {}, acc11 = {}, acc12 = {}, acc13 = {};

  #pragma unroll
  for (int kt = 0; kt < 16; ++kt) {
    if (kt + 2 < 16) LOADB(bC, kt + 2);
    const short8 a0 = *(const short8*)((const char*)Alds + ((abase0 + (unsigned)kt * 64) ^ aswz0));
    const short8 a1 = *(const short8*)((const char*)Alds + ((abase1 + (unsigned)kt * 64) ^ aswz1));
    acc00 = __builtin_amdgcn_mfma_f32_16x16x32_bf16(a0, bA0, acc00, 0, 0, 0);
    acc10 = __builtin_amdgcn_mfma_f32_16x16x32_bf16(a1, bA0, acc10, 0, 0, 0);
    acc01 = __builtin_amdgcn_mfma_f32_16x16x32_bf16(a0, bA1, acc01, 0, 0, 0);
    acc11 = __builtin_amdgcn_mfma_f32_16x16x32_bf16(a1, bA1, acc11, 0, 0, 0);
    acc02 = __builtin_amdgcn_mfma_f32_16x16x32_bf16(a0, bA2, acc02, 0, 0, 0);
    acc12 = __builtin_amdgcn_mfma_f32_16x16x32_bf16(a1, bA2, acc12, 0, 0, 0);
    acc03 = __builtin_amdgcn_mfma_f32_16x16x32_bf16(a0, bA3, acc03, 0, 0, 0);
    acc13 = __builtin_amdgcn_mfma_f32_16x16x32_bf16(a1, bA3, acc13, 0, 0, 0);
    // rotate ring (SSA renaming: these are free with full unroll)
    bA0 = bB0; bA1 = bB1; bA2 = bB2; bA3 = bB3;
    bB0 = bC0; bB1 = bC1; bB2 = bC2; bB3 = bC3;
  }
#undef LOADB

  // ---------------- epilogue: out = x + acc + bias ----------------
  f32x4 accs[2][4] = {{acc00, acc01, acc02, acc03}, {acc10, acc11, acc12, acc13}};
  #pragma unroll
  for (int m = 0; m < 2; ++m) {
    #pragma unroll
    for (int nt = 0; nt < 4; ++nt) {
      const int col = wn * 64 + nt * 16 + lo;
      const float bv = bias[col];
      #pragma unroll
      for (int q = 0; q < 4; ++q) {
        const int rloc = m * 16 + hi * 4 + q;      // C/D: row = 4*hi + reg
        const float xv = bf2f(Xlds[rloc * 528 + col]);
        out[(row0 + rloc) * DD + col] = xv + accs[m][nt][q] + bv;
      }
    }
  }
}

extern "C" void kernel_launch(void* const* d_in, const int* in_sizes, int n_in,
                              void* d_out, int out_size, void* d_ws, size_t ws_size,
                              hipStream_t stream) {
  const float* x    = (const float*)d_in[0];
  const float* lns  = (const float*)d_in[1];
  const float* lnb  = (const float*)d_in[2];
  const float* W    = (const float*)d_in[3];
  const float* bias = (const float*)d_in[4];
  float* out = (float*)d_out;
  unsigned short* Bt = (unsigned short*)d_ws;   // 512*512*2 = 512KB scratch

  const int nrows = in_sizes[0] / DD;

  dim3 tb(32, 8), tg(DD / 32, DD / 32);
  prep_bt<<<tg, tb, 0, stream>>>(W, Bt);
  fused_ln_gemm<<<nrows / BM, THREADS, 0, stream>>>(x, lns, lnb, Bt, bias, out);
}

// Round 3
// 336.663 us; speedup vs baseline: 2.9947x; 1.7322x over previous
//
#include <hip/hip_runtime.h>
#include <hip/hip_bf16.h>

#define DD 512
#define BM 32
#define THREADS 512

typedef __attribute__((ext_vector_type(8))) short short8;   // 8 bf16 = 4 VGPRs (MFMA A/B frag)
typedef __attribute__((ext_vector_type(4))) float f32x4;    // MFMA C/D frag

__device__ __forceinline__ unsigned short f2bf(float f) {
  union { float f; unsigned u; } v; v.f = f;
  unsigned r = v.u + 0x7FFFu + ((v.u >> 16) & 1u);  // RNE
  return (unsigned short)(r >> 16);
}
__device__ __forceinline__ float bf2f(unsigned short u) {
  union { unsigned u; float f; } v; v.u = ((unsigned)u) << 16;
  return v.f;
}

// Pack kernel (K x N fp32, row-major) into MFMA-fragment-major bf16:
//   Bpack[((nb*16 + kt)*64 + lane)*8 + j]  holds  B[k][n]
//   with n = nb*16 + (lane&15), k = kt*32 + (lane>>4)*8 + j.
// A wave's B-frag load for (nb,kt) is then base + lane*16B -> contiguous 1KB.
__global__ void prep_bpack(const float* __restrict__ W, unsigned short* __restrict__ Bpack) {
  const int tid = blockIdx.x * blockDim.x + threadIdx.x;   // 262144 threads
  const int n = tid & 511, k = tid >> 9;
  const float w = W[(size_t)k * DD + n];                   // coalesced read
  const int nb = n >> 4, lo = n & 15;
  const int kt = k >> 5, hi = (k >> 3) & 3, j = k & 7;
  const int lane = hi * 16 + lo;
  Bpack[(((size_t)(nb * 16 + kt)) * 64 + lane) * 8 + j] = f2bf(w);
}

// Fused: LN -> relu -> (bf16 cast) -> GEMM vs Bpack -> +x +bias
// block: 32 rows x full 512 cols; 8 waves each own a 32x64 output strip.
__global__ __launch_bounds__(THREADS, 4)
void fused_ln_gemm(const float* __restrict__ x, const float* __restrict__ lns,
                   const float* __restrict__ lnb, const unsigned short* __restrict__ Bpack,
                   const float* __restrict__ bias, float* __restrict__ out) {
  __shared__ unsigned short Alds[BM * 512];   // h bf16, XOR-swizzled rows (1KB row)
  __shared__ unsigned short Xlds[BM * 528];   // x bf16, padded stride (1056B row)

  const int t = threadIdx.x;
  const long row0 = (long)blockIdx.x * BM;

  // ---------------- LN + relu phase: 16 threads per row ----------------
  {
    const int r = t >> 4, g = t & 15;
    const float* xr = x + (row0 + r) * DD + g * 4;
    float4 v[8];
    float s = 0.f, s2 = 0.f;
    #pragma unroll
    for (int i = 0; i < 8; ++i) {
      v[i] = *(const float4*)(xr + i * 64);
      s  += (v[i].x + v[i].y) + (v[i].z + v[i].w);
      s2 += v[i].x * v[i].x + v[i].y * v[i].y + v[i].z * v[i].z + v[i].w * v[i].w;
    }
    #pragma unroll
    for (int m = 1; m < 16; m <<= 1) {   // 16-lane group reduce (within wave)
      s  += __shfl_xor(s,  m, 64);
      s2 += __shfl_xor(s2, m, 64);
    }
    const float mu   = s * (1.f / 512.f);
    const float var  = fmaxf(s2 * (1.f / 512.f) - mu * mu, 0.f);
    const float rstd = rsqrtf(var + 1e-6f);
    #pragma unroll
    for (int i = 0; i < 8; ++i) {
      const int c = g * 4 + i * 64;
      const float4 sc = *(const float4*)(lns + c);
      const float4 bi = *(const float4*)(lnb + c);
      float h0 = fmaxf((v[i].x - mu) * rstd * sc.x + bi.x, 0.f);
      float h1 = fmaxf((v[i].y - mu) * rstd * sc.y + bi.y, 0.f);
      float h2 = fmaxf((v[i].z - mu) * rstd * sc.z + bi.z, 0.f);
      float h3 = fmaxf((v[i].w - mu) * rstd * sc.w + bi.w, 0.f);
      ushort4 hu = { f2bf(h0), f2bf(h1), f2bf(h2), f2bf(h3) };
      ushort4 xu = { f2bf(v[i].x), f2bf(v[i].y), f2bf(v[i].z), f2bf(v[i].w) };
      // A: byte addr (r*1024 + c*2) ^ ((r&7)<<4)  — 8B-aligned stays 8B-aligned
      unsigned a = (unsigned)(r * 1024 + g * 8 + i * 128) ^ (unsigned)((r & 7) << 4);
      *(ushort4*)((char*)Alds + a) = hu;
      *(ushort4*)(&Xlds[r * 528 + c]) = xu;
    }
  }
  __syncthreads();

  // ---------------- GEMM phase (no barriers, depth-2 B prefetch) -------
  const int lane = t & 63, lo = lane & 15, hi = lane >> 4;
  const int wn = t >> 6;                       // 0..7: wave's 64-col strip

  // A frag byte addrs for the two 16-row sub-tiles (m = 0,1)
  unsigned abase0, aswz0, abase1, aswz1;
  {
    const int r0 = lo;        abase0 = (unsigned)(r0 * 1024 + hi * 16); aswz0 = (unsigned)((r0 & 7) << 4);
    const int r1 = 16 + lo;   abase1 = (unsigned)(r1 * 1024 + hi * 16); aswz1 = (unsigned)((r1 & 7) << 4);
  }
  // B frag (nb = wn*4 + nt, kt): Bpack8 + (nb*16 + kt)*64 + lane  (16B units)
  const short8* bbase = (const short8*)Bpack + (size_t)wn * 4096 + lane;

#define LOADB(dst, kt)                                                        \
  { dst##0 = bbase[(0 * 16 + (kt)) * 64];                                     \
    dst##1 = bbase[(1 * 16 + (kt)) * 64];                                     \
    dst##2 = bbase[(2 * 16 + (kt)) * 64];                                     \
    dst##3 = bbase[(3 * 16 + (kt)) * 64]; }

  short8 bA0, bA1, bA2, bA3, bB0, bB1, bB2, bB3, bC0, bC1, bC2, bC3;
  LOADB(bA, 0);
  LOADB(bB, 1);

  f32x4 acc00 = {}, acc01 = {}, acc02 = {}, acc03 = {};
  f32x4 acc10 = {}, acc11 = {}, acc12 = {}, acc13 = {};

  #pragma unroll
  for (int kt = 0; kt < 16; ++kt) {
    if (kt + 2 < 16) LOADB(bC, kt + 2);
    const short8 a0 = *(const short8*)((const char*)Alds + ((abase0 + (unsigned)kt * 64) ^ aswz0));
    const short8 a1 = *(const short8*)((const char*)Alds + ((abase1 + (unsigned)kt * 64) ^ aswz1));
    acc00 = __builtin_amdgcn_mfma_f32_16x16x32_bf16(a0, bA0, acc00, 0, 0, 0);
    acc10 = __builtin_amdgcn_mfma_f32_16x16x32_bf16(a1, bA0, acc10, 0, 0, 0);
    acc01 = __builtin_amdgcn_mfma_f32_16x16x32_bf16(a0, bA1, acc01, 0, 0, 0);
    acc11 = __builtin_amdgcn_mfma_f32_16x16x32_bf16(a1, bA1, acc11, 0, 0, 0);
    acc02 = __builtin_amdgcn_mfma_f32_16x16x32_bf16(a0, bA2, acc02, 0, 0, 0);
    acc12 = __builtin_amdgcn_mfma_f32_16x16x32_bf16(a1, bA2, acc12, 0, 0, 0);
    acc03 = __builtin_amdgcn_mfma_f32_16x16x32_bf16(a0, bA3, acc03, 0, 0, 0);
    acc13 = __builtin_amdgcn_mfma_f32_16x16x32_bf16(a1, bA3, acc13, 0, 0, 0);
    // rotate ring (SSA renaming: free with full unroll)
    bA0 = bB0; bA1 = bB1; bA2 = bB2; bA3 = bB3;
    bB0 = bC0; bB1 = bC1; bB2 = bC2; bB3 = bC3;
  }
#undef LOADB

  // ---------------- epilogue: out = x + acc + bias ----------------
  f32x4 accs[2][4] = {{acc00, acc01, acc02, acc03}, {acc10, acc11, acc12, acc13}};
  #pragma unroll
  for (int m = 0; m < 2; ++m) {
    #pragma unroll
    for (int nt = 0; nt < 4; ++nt) {
      const int col = wn * 64 + nt * 16 + lo;
      const float bv = bias[col];
      #pragma unroll
      for (int q = 0; q < 4; ++q) {
        const int rloc = m * 16 + hi * 4 + q;      // C/D: row = 4*hi + reg
        const float xv = bf2f(Xlds[rloc * 528 + col]);
        out[(row0 + rloc) * DD + col] = xv + accs[m][nt][q] + bv;
      }
    }
  }
}

extern "C" void kernel_launch(void* const* d_in, const int* in_sizes, int n_in,
                              void* d_out, int out_size, void* d_ws, size_t ws_size,
                              hipStream_t stream) {
  const float* x    = (const float*)d_in[0];
  const float* lns  = (const float*)d_in[1];
  const float* lnb  = (const float*)d_in[2];
  const float* W    = (const float*)d_in[3];
  const float* bias = (const float*)d_in[4];
  float* out = (float*)d_out;
  unsigned short* Bpack = (unsigned short*)d_ws;   // 512*512*2 = 512KB scratch

  const int nrows = in_sizes[0] / DD;

  prep_bpack<<<DD * DD / 256, 256, 0, stream>>>(W, Bpack);
  fused_ln_gemm<<<nrows / BM, THREADS, 0, stream>>>(x, lns, lnb, Bpack, bias, out);
}